// Round 18
// baseline (169.049 us; speedup 1.0000x reference)
//
#include <hip/hip_runtime.h>
#include <hip/hip_fp16.h>

#define NN 50000
#define EE 800000
#define DD 96
#define GG 64
#define NH 12    // uint4 (8-half) chunks per 96-half row

#define FPSCALE 16777216.0f           // 2^24 fixed-point for weight sums
#define MASK44 ((1ULL << 44) - 1)
#define NCPY 16  // histogram copies
#define PAD 64   // padded CSR slots per node (max degree ~45, Poisson(16))

typedef unsigned long long u64;
typedef __attribute__((ext_vector_type(8))) _Float16 half8;
typedef __attribute__((ext_vector_type(4))) float f32x4;

__device__ __forceinline__ uint4 pack8(const float* f) {
    __half2 h0 = __floats2half2_rn(f[0], f[1]);
    __half2 h1 = __floats2half2_rn(f[2], f[3]);
    __half2 h2 = __floats2half2_rn(f[4], f[5]);
    __half2 h3 = __floats2half2_rn(f[6], f[7]);
    uint4 o;
    o.x = *(unsigned int*)&h0; o.y = *(unsigned int*)&h1;
    o.z = *(unsigned int*)&h2; o.w = *(unsigned int*)&h3;
    return o;
}

__device__ __forceinline__ void cvt8(uint4 v, float* f) {
    const __half2* h = (const __half2*)&v;
    #pragma unroll
    for (int k = 0; k < 4; ++k) {
        float2 t = __half22float2(h[k]);
        f[2 * k] = t.x; f[2 * k + 1] = t.y;
    }
}

// ---------------- pre-pass: zero state + fp16 conversions + W transposes ----------------

__global__ void k_pre(u64* histo, float* gsum,
                      const float4* __restrict__ x, uint4* __restrict__ xh,
                      const float* __restrict__ W1, _Float16* __restrict__ w1t,
                      const float* __restrict__ W3, _Float16* __restrict__ w3t) {
    int i = blockIdx.x * 256 + threadIdx.x;
    if (i < NCPY * NN) histo[i] = 0ULL;
    if (i < GG * DD) gsum[i] = 0.f;
    if (i < DD * DD) {              // Wt[n][k] = W[k][n], fp16
        int k = i / DD, n = i % DD;
        w1t[n * DD + k] = (_Float16)W1[i];
        w3t[n * DD + k] = (_Float16)W3[i];
    }
    if (i < NN * DD / 8) {
        float4 f0 = x[2 * i], f1 = x[2 * i + 1];
        float f[8] = {f0.x, f0.y, f0.z, f0.w, f1.x, f1.y, f1.z, f1.w};
        xh[i] = pack8(f);
    }
}

// ---------------- histogram: 1 u64 atomic per edge, 16 copies ----------------

__global__ void k_hist(const int* __restrict__ dst, const float* __restrict__ ew,
                       u64* histo, unsigned int* rank) {
    int e = blockIdx.x * 256 + threadIdx.x;
    int cpy = blockIdx.x & (NCPY - 1);
    if (e < EE) {
        u64 q = (u64)(ew[e] * FPSCALE + 0.5f);
        u64 old = atomicAdd(&histo[(size_t)cpy * NN + dst[e]], (1ULL << 44) | q);
        rank[e] = ((unsigned)cpy << 24) | (unsigned)(old >> 44);
    }
}

// ---------------- reduce 16 copies: dinv, counts, per-copy byte offsets ----------------

__global__ __launch_bounds__(256) void k_dinv(const u64* __restrict__ histo,
                                              float* dinv, int* cnts,
                                              unsigned char* xoffB) {
    int i = blockIdx.x * 256 + threadIdx.x;
    if (i >= NN) return;
    u64 wsum44 = 0;
    unsigned pre = 0;
    unsigned char ob[NCPY];
    #pragma unroll
    for (int x = 0; x < NCPY; ++x) {
        u64 h = histo[(size_t)x * NN + i];
        wsum44 += h & MASK44;
        ob[x] = (unsigned char)pre;
        pre += (unsigned)(h >> 44);
    }
    cnts[i] = (int)pre;
    dinv[i] = rsqrtf(1.0f + (float)wsum44 * (1.0f / FPSCALE));
    *(uint4*)&xoffB[(size_t)i * NCPY] = *(uint4*)ob;   // NCPY==16 bytes
}

// ---------------- scatter (no atomics, no row_ptr) ----------------

__global__ void k_scatter(const int* __restrict__ src, const int* __restrict__ dst,
                          const float* __restrict__ ew, const float* __restrict__ dinv,
                          const unsigned char* __restrict__ xoffB,
                          const unsigned int* __restrict__ rank, int2* csr) {
    int e = blockIdx.x * 256 + threadIdx.x;
    if (e < EE) {
        int s = src[e], d = dst[e];
        unsigned r = rank[e];
        int x = (int)(r >> 24);
        int p = d * PAD + (int)xoffB[(size_t)d * NCPY + x] + (int)(r & 0xFFFFFFu);
        float w = dinv[s] * ew[e] * dinv[d];
        csr[p] = make_int2(s, __float_as_int(w));
    }
}

// ---------------- FUSED propagate + MFMA GEMM ----------------
// 192 threads = 16 nodes x 12 chunks. Gather phase (x2-unrolled padded-CSR walk)
// packs each node row (fp16) into LDS (stride 13 -> conflict-free b128 reads).
// Then wave 0 computes the 16x96 output tile with 18 MFMAs; B-frags from
// global Wt (L2-hot), A-frags from LDS.
// L==1: out = relu(P@W1+b1) -> fp16 Oh.  L==2: P -> Ph (pool), out = P@W3+b3 -> f32 embed.

template<int L>
__global__ __launch_bounds__(192) void k_prop_gemm(const uint4* __restrict__ Th,
                                                   const int2* __restrict__ csr,
                                                   const int* __restrict__ cnts,
                                                   const float* __restrict__ dinv,
                                                   const _Float16* __restrict__ Wt,
                                                   const float* __restrict__ bias,
                                                   _Float16* __restrict__ Oh,
                                                   float* __restrict__ embed,
                                                   uint4* __restrict__ Ph) {
    __shared__ uint4 sA[16 * 13];
    int tid = threadIdx.x;
    int n = tid / 12, c = tid % 12;
    int node = blockIdx.x * 16 + n;            // grid = NN/16 exactly
    float di = dinv[node];
    float self = di * di;
    float f[8], g[8], acc[8];
    cvt8(Th[node * NH + c], f);
    #pragma unroll
    for (int j = 0; j < 8; ++j) acc[j] = self * f[j];
    int e0 = node * PAD, e1 = e0 + cnts[node];
    int e = e0;
    for (; e + 1 < e1; e += 2) {
        int2 sa = csr[e];
        int2 sb = csr[e + 1];
        float wa = __int_as_float(sa.y);
        float wb = __int_as_float(sb.y);
        cvt8(Th[sa.x * NH + c], f);
        cvt8(Th[sb.x * NH + c], g);
        #pragma unroll
        for (int j = 0; j < 8; ++j) acc[j] = fmaf(wa, f[j], acc[j]);
        #pragma unroll
        for (int j = 0; j < 8; ++j) acc[j] = fmaf(wb, g[j], acc[j]);
    }
    if (e < e1) {
        int2 sw = csr[e];
        float w = __int_as_float(sw.y);
        cvt8(Th[sw.x * NH + c], f);
        #pragma unroll
        for (int j = 0; j < 8; ++j) acc[j] = fmaf(w, f[j], acc[j]);
    }
    uint4 pk = pack8(acc);
    sA[n * 13 + c] = pk;
    if (L == 2) Ph[node * NH + c] = pk;        // P2 kept for the pool
    __syncthreads();

    if (tid < 64) {                            // wave 0: 16x96 MFMA tile
        int r = tid & 15, q = tid >> 4;
        half8 bf[3][6];
        #pragma unroll
        for (int ks = 0; ks < 3; ++ks)
            #pragma unroll
            for (int nt = 0; nt < 6; ++nt)
                bf[ks][nt] = *(const half8*)&Wt[(size_t)(nt * 16 + r) * DD + ks * 32 + q * 8];
        f32x4 av[6];
        #pragma unroll
        for (int nt = 0; nt < 6; ++nt) { float b = bias[nt * 16 + r]; av[nt] = (f32x4){b, b, b, b}; }
        #pragma unroll
        for (int ks = 0; ks < 3; ++ks) {
            half8 af = *(const half8*)&sA[r * 13 + ks * 4 + q];
            #pragma unroll
            for (int nt = 0; nt < 6; ++nt)
                av[nt] = __builtin_amdgcn_mfma_f32_16x16x32_f16(af, bf[ks][nt], av[nt], 0, 0, 0);
        }
        int rowbase = blockIdx.x * 16 + q * 4;
        #pragma unroll
        for (int nt = 0; nt < 6; ++nt)
            #pragma unroll
            for (int gi = 0; gi < 4; ++gi) {
                if (L == 1) {
                    float v = fmaxf(av[nt][gi], 0.f);
                    Oh[(size_t)(rowbase + gi) * DD + nt * 16 + r] = (_Float16)v;
                } else {
                    embed[(size_t)(rowbase + gi) * DD + nt * 16 + r] = av[nt][gi];
                }
            }
    }
}

// ---------------- pool stage A: per-graph striped partial sums (fp16 P2) ----------------

__global__ __launch_bounds__(256) void k_pool_a(const __half* __restrict__ P2,
                                                const int* __restrict__ batch,
                                                float* __restrict__ gsum) {
    int b = blockIdx.x;
    int g = b >> 3, s = b & 7;
    int tid = threadIdx.x;
    int d = tid % 96, t = tid / 96;            // t in {0,1} for tid<192
    int lo = 0, hi = NN;
    while (lo < hi) { int m = (lo + hi) >> 1; if (batch[m] < g) lo = m + 1; else hi = m; }
    int start = lo;
    lo = 0; hi = NN;
    while (lo < hi) { int m = (lo + hi) >> 1; if (batch[m] < g + 1) lo = m + 1; else hi = m; }
    int end = lo;
    float acc = 0.f;
    if (tid < 192)
        for (int i = start + s * 2 + t; i < end; i += 16)
            acc += __half2float(P2[(size_t)i * DD + d]);
    __shared__ float red[192];
    if (tid < 192) red[tid] = acc;
    __syncthreads();
    if (tid < 96) atomicAdd(&gsum[g * 96 + tid], red[tid] + red[tid + 96]);
}

// ---------------- pool stage B: outG = gsum @ W4 + cnt * b4 ----------------

__global__ __launch_bounds__(96) void k_pool_b(const float* __restrict__ gsum,
                                               const int* __restrict__ batch,
                                               const float* __restrict__ W4,
                                               const float* __restrict__ b4,
                                               float* __restrict__ outG) {
    int g = blockIdx.x, d = threadIdx.x;
    __shared__ float srow[96];
    srow[d] = gsum[g * 96 + d];
    int lo = 0, hi = NN;
    while (lo < hi) { int m = (lo + hi) >> 1; if (batch[m] < g) lo = m + 1; else hi = m; }
    int start = lo;
    lo = 0; hi = NN;
    while (lo < hi) { int m = (lo + hi) >> 1; if (batch[m] < g + 1) lo = m + 1; else hi = m; }
    int end = lo;
    __syncthreads();
    float o = (float)(end - start) * b4[d];
    #pragma unroll 8
    for (int k = 0; k < 96; ++k) o = fmaf(srow[k], W4[k * 96 + d], o);
    outG[g * 96 + d] = o;
}

// ---------------- launch ----------------

extern "C" void kernel_launch(void* const* d_in, const int* in_sizes, int n_in,
                              void* d_out, int out_size, void* d_ws, size_t ws_size,
                              hipStream_t stream) {
    const float* x  = (const float*)d_in[0];
    const float* W1 = (const float*)d_in[1];
    const float* b1 = (const float*)d_in[2];
    const float* W3 = (const float*)d_in[3];
    const float* b3 = (const float*)d_in[4];
    const float* W4 = (const float*)d_in[5];
    const float* b4 = (const float*)d_in[6];
    const float* ew = (const float*)d_in[7];
    const int* ei   = (const int*)d_in[8];
    const int* src  = ei;
    const int* dst  = ei + EE;
    const int* batch = (const int*)d_in[9];

    float* out_embed = (float*)d_out;
    float* out_graph = out_embed + (size_t)NN * DD;

    char* w = (char*)d_ws;
    auto alloc = [&](size_t bytes) { char* p = w; w += (bytes + 255) & ~(size_t)255; return p; };
    u64* histo     = (u64*)  alloc((size_t)NCPY * NN * 8);   // 6.4 MB
    unsigned* rank = (unsigned*)alloc((size_t)EE * 4);
    float* dinv    = (float*)alloc((size_t)NN * 4);
    int*   cnts    = (int*)  alloc((size_t)NN * 4);
    unsigned char* xoffB = (unsigned char*)alloc((size_t)NN * NCPY);
    float* gsum    = (float*)alloc((size_t)GG * DD * 4);
    int2*  csr     = (int2*) alloc((size_t)NN * PAD * 8);    // 25.6 MB padded
    char*  xh      = alloc((size_t)NN * DD * 2);             // fp16 x
    char*  hh      = alloc((size_t)NN * DD * 2);             // fp16 h
    char*  ph      = alloc((size_t)NN * DD * 2);             // fp16 P2
    _Float16* w1t  = (_Float16*)alloc((size_t)DD * DD * 2);
    _Float16* w3t  = (_Float16*)alloc((size_t)DD * DD * 2);

    int nbN = (NN + 255) / 256;            // 196
    int nbE = (EE + 255) / 256;            // 3125
    int nbZ = (NCPY * NN + 255) / 256;     // 3125 (covers histo zero + x cvt)

    k_pre<<<nbZ, 256, 0, stream>>>(histo, gsum, (const float4*)x, (uint4*)xh,
                                   W1, w1t, W3, w3t);
    k_hist<<<nbE, 256, 0, stream>>>(dst, ew, histo, rank);
    k_dinv<<<nbN, 256, 0, stream>>>(histo, dinv, cnts, xoffB);
    k_scatter<<<nbE, 256, 0, stream>>>(src, dst, ew, dinv, xoffB, rank, csr);

    // h = relu((A_hat x) W1 + b1) [fused gather+MFMA, fp16 out]
    k_prop_gemm<1><<<NN / 16, 192, 0, stream>>>((const uint4*)xh, csr, cnts, dinv,
                                                w1t, b1, (_Float16*)hh, nullptr, nullptr);
    // P2 = A_hat h [fp16, kept] ; embed = P2 W3 + b3 [fused, f32 out]
    k_prop_gemm<2><<<NN / 16, 192, 0, stream>>>((const uint4*)hh, csr, cnts, dinv,
                                                w3t, b3, nullptr, out_embed, (uint4*)ph);
    // out_graph = pool(P2) @ W4 + cnt * b4
    k_pool_a<<<GG * 8, 256, 0, stream>>>((const __half*)ph, batch, gsum);
    k_pool_b<<<GG, 96, 0, stream>>>(gsum, batch, W4, b4, out_graph);
}

// Round 19
// 156.154 us; speedup vs baseline: 1.0826x; 1.0826x over previous
//
#include <hip/hip_runtime.h>
#include <hip/hip_fp16.h>

#define NN 50000
#define EE 800000
#define DD 96
#define GG 64
#define NH 12    // uint4 (8-half) chunks per 96-half row

#define FPSCALE 16777216.0f           // 2^24 fixed-point for weight sums
#define MASK44 ((1ULL << 44) - 1)
#define NCPY 16  // histogram copies
#define PAD 64   // padded CSR slots per node (max degree ~45, Poisson(16))

typedef unsigned long long u64;
typedef __attribute__((ext_vector_type(8))) _Float16 half8;
typedef __attribute__((ext_vector_type(4))) float f32x4;

__device__ __forceinline__ uint4 pack8(const float* f) {
    __half2 h0 = __floats2half2_rn(f[0], f[1]);
    __half2 h1 = __floats2half2_rn(f[2], f[3]);
    __half2 h2 = __floats2half2_rn(f[4], f[5]);
    __half2 h3 = __floats2half2_rn(f[6], f[7]);
    uint4 o;
    o.x = *(unsigned int*)&h0; o.y = *(unsigned int*)&h1;
    o.z = *(unsigned int*)&h2; o.w = *(unsigned int*)&h3;
    return o;
}

__device__ __forceinline__ void cvt8(uint4 v, float* f) {
    const __half2* h = (const __half2*)&v;
    #pragma unroll
    for (int k = 0; k < 4; ++k) {
        float2 t = __half22float2(h[k]);
        f[2 * k] = t.x; f[2 * k + 1] = t.y;
    }
}

// ---------------- pre-pass: zero state + fp16 conversions + W transposes ----------------

__global__ void k_pre(u64* histo, float* outG,
                      const float4* __restrict__ x, uint4* __restrict__ xh,
                      const float* __restrict__ W1, _Float16* __restrict__ w1t,
                      const float* __restrict__ W3, _Float16* __restrict__ w3t) {
    int i = blockIdx.x * 256 + threadIdx.x;
    if (i < NCPY * NN) histo[i] = 0ULL;
    if (i < GG * DD) outG[i] = 0.f;            // out_graph accumulated by pool atomics
    if (i < DD * DD) {              // Wt[n][k] = W[k][n], fp16
        int k = i / DD, n = i % DD;
        w1t[n * DD + k] = (_Float16)W1[i];
        w3t[n * DD + k] = (_Float16)W3[i];
    }
    if (i < NN * DD / 8) {
        float4 f0 = x[2 * i], f1 = x[2 * i + 1];
        float f[8] = {f0.x, f0.y, f0.z, f0.w, f1.x, f1.y, f1.z, f1.w};
        xh[i] = pack8(f);
    }
}

// ---------------- histogram: 1 u64 atomic per edge, 16 copies ----------------

__global__ void k_hist(const int* __restrict__ dst, const float* __restrict__ ew,
                       u64* histo, unsigned int* rank) {
    int e = blockIdx.x * 256 + threadIdx.x;
    int cpy = blockIdx.x & (NCPY - 1);
    if (e < EE) {
        u64 q = (u64)(ew[e] * FPSCALE + 0.5f);
        u64 old = atomicAdd(&histo[(size_t)cpy * NN + dst[e]], (1ULL << 44) | q);
        rank[e] = ((unsigned)cpy << 24) | (unsigned)(old >> 44);
    }
}

// ---------------- reduce 16 copies: dinv, counts, per-copy byte offsets ----------------

__global__ __launch_bounds__(256) void k_dinv(const u64* __restrict__ histo,
                                              float* dinv, int* cnts,
                                              unsigned char* xoffB) {
    int i = blockIdx.x * 256 + threadIdx.x;
    if (i >= NN) return;
    u64 wsum44 = 0;
    unsigned pre = 0;
    unsigned char ob[NCPY];
    #pragma unroll
    for (int x = 0; x < NCPY; ++x) {
        u64 h = histo[(size_t)x * NN + i];
        wsum44 += h & MASK44;
        ob[x] = (unsigned char)pre;
        pre += (unsigned)(h >> 44);
    }
    cnts[i] = (int)pre;
    dinv[i] = rsqrtf(1.0f + (float)wsum44 * (1.0f / FPSCALE));
    *(uint4*)&xoffB[(size_t)i * NCPY] = *(uint4*)ob;   // NCPY==16 bytes
}

// ---------------- scatter (no atomics, no row_ptr) ----------------

__global__ void k_scatter(const int* __restrict__ src, const int* __restrict__ dst,
                          const float* __restrict__ ew, const float* __restrict__ dinv,
                          const unsigned char* __restrict__ xoffB,
                          const unsigned int* __restrict__ rank, int2* csr) {
    int e = blockIdx.x * 256 + threadIdx.x;
    if (e < EE) {
        int s = src[e], d = dst[e];
        unsigned r = rank[e];
        int x = (int)(r >> 24);
        int p = d * PAD + (int)xoffB[(size_t)d * NCPY + x] + (int)(r & 0xFFFFFFu);
        float w = dinv[s] * ew[e] * dinv[d];
        csr[p] = make_int2(s, __float_as_int(w));
    }
}

// ---------------- FUSED propagate + MFMA GEMM ----------------
// 192 threads = 16 nodes x 12 chunks; x4-unrolled padded-CSR gather -> LDS
// (stride 13, conflict-free) -> wave 0 does the 16x96 tile with 18 MFMAs.

template<int L>
__global__ __launch_bounds__(192) void k_prop_gemm(const uint4* __restrict__ Th,
                                                   const int2* __restrict__ csr,
                                                   const int* __restrict__ cnts,
                                                   const float* __restrict__ dinv,
                                                   const _Float16* __restrict__ Wt,
                                                   const float* __restrict__ bias,
                                                   _Float16* __restrict__ Oh,
                                                   float* __restrict__ embed,
                                                   uint4* __restrict__ Ph) {
    __shared__ uint4 sA[16 * 13];
    int tid = threadIdx.x;
    int n = tid / 12, c = tid % 12;
    int node = blockIdx.x * 16 + n;            // grid = NN/16 exactly
    float di = dinv[node];
    float self = di * di;
    float f0[8], f1[8], f2[8], f3[8], acc[8];
    cvt8(Th[node * NH + c], f0);
    #pragma unroll
    for (int j = 0; j < 8; ++j) acc[j] = self * f0[j];
    int e0 = node * PAD, e1 = e0 + cnts[node];
    int e = e0;
    for (; e + 3 < e1; e += 4) {
        int2 sa = csr[e], sb = csr[e + 1], sc = csr[e + 2], sd = csr[e + 3];
        float wa = __int_as_float(sa.y), wb = __int_as_float(sb.y);
        float wc = __int_as_float(sc.y), wd = __int_as_float(sd.y);
        cvt8(Th[sa.x * NH + c], f0);
        cvt8(Th[sb.x * NH + c], f1);
        cvt8(Th[sc.x * NH + c], f2);
        cvt8(Th[sd.x * NH + c], f3);
        #pragma unroll
        for (int j = 0; j < 8; ++j) acc[j] = fmaf(wa, f0[j], acc[j]);
        #pragma unroll
        for (int j = 0; j < 8; ++j) acc[j] = fmaf(wb, f1[j], acc[j]);
        #pragma unroll
        for (int j = 0; j < 8; ++j) acc[j] = fmaf(wc, f2[j], acc[j]);
        #pragma unroll
        for (int j = 0; j < 8; ++j) acc[j] = fmaf(wd, f3[j], acc[j]);
    }
    for (; e < e1; ++e) {
        int2 sw = csr[e];
        float w = __int_as_float(sw.y);
        cvt8(Th[sw.x * NH + c], f0);
        #pragma unroll
        for (int j = 0; j < 8; ++j) acc[j] = fmaf(w, f0[j], acc[j]);
    }
    uint4 pk = pack8(acc);
    sA[n * 13 + c] = pk;
    if (L == 2) Ph[node * NH + c] = pk;        // P2 kept for the pool
    __syncthreads();

    if (tid < 64) {                            // wave 0: 16x96 MFMA tile
        int r = tid & 15, q = tid >> 4;
        half8 bf[3][6];
        #pragma unroll
        for (int ks = 0; ks < 3; ++ks)
            #pragma unroll
            for (int nt = 0; nt < 6; ++nt)
                bf[ks][nt] = *(const half8*)&Wt[(size_t)(nt * 16 + r) * DD + ks * 32 + q * 8];
        f32x4 av[6];
        #pragma unroll
        for (int nt = 0; nt < 6; ++nt) { float b = bias[nt * 16 + r]; av[nt] = (f32x4){b, b, b, b}; }
        #pragma unroll
        for (int ks = 0; ks < 3; ++ks) {
            half8 af = *(const half8*)&sA[r * 13 + ks * 4 + q];
            #pragma unroll
            for (int nt = 0; nt < 6; ++nt)
                av[nt] = __builtin_amdgcn_mfma_f32_16x16x32_f16(af, bf[ks][nt], av[nt], 0, 0, 0);
        }
        int rowbase = blockIdx.x * 16 + q * 4;
        #pragma unroll
        for (int nt = 0; nt < 6; ++nt)
            #pragma unroll
            for (int gi = 0; gi < 4; ++gi) {
                if (L == 1) {
                    float v = fmaxf(av[nt][gi], 0.f);
                    Oh[(size_t)(rowbase + gi) * DD + nt * 16 + r] = (_Float16)v;
                } else {
                    embed[(size_t)(rowbase + gi) * DD + nt * 16 + r] = av[nt][gi];
                }
            }
    }
}

// ---------------- pool (single stage): partial sums -> W4 projection -> atomics ----------------
// 512 blocks (8 per graph). Each projects its PARTIAL sum through W4 (linear op)
// and atomicAdds 96 floats into out_graph (zeroed in k_pre). s==0 adds cnt*b4.

__global__ __launch_bounds__(256) void k_pool(const __half* __restrict__ P2,
                                              const int* __restrict__ batch,
                                              const float* __restrict__ W4,
                                              const float* __restrict__ b4,
                                              float* __restrict__ outG) {
    int b = blockIdx.x;
    int g = b >> 3, s = b & 7;
    int tid = threadIdx.x;
    int d = tid % 96, t = tid / 96;            // t in {0,1} for tid<192
    int lo = 0, hi = NN;
    while (lo < hi) { int m = (lo + hi) >> 1; if (batch[m] < g) lo = m + 1; else hi = m; }
    int start = lo;
    lo = 0; hi = NN;
    while (lo < hi) { int m = (lo + hi) >> 1; if (batch[m] < g + 1) lo = m + 1; else hi = m; }
    int end = lo;
    float acc = 0.f;
    if (tid < 192)
        for (int i = start + s * 2 + t; i < end; i += 16)
            acc += __half2float(P2[(size_t)i * DD + d]);
    __shared__ float red[192];
    __shared__ float srow[96];
    if (tid < 192) red[tid] = acc;
    __syncthreads();
    if (tid < 96) srow[tid] = red[tid] + red[tid + 96];
    __syncthreads();
    if (tid < 96) {
        float o = (s == 0) ? (float)(end - start) * b4[tid] : 0.f;
        #pragma unroll 8
        for (int k = 0; k < 96; ++k) o = fmaf(srow[k], W4[k * 96 + tid], o);
        atomicAdd(&outG[g * 96 + tid], o);
    }
}

// ---------------- launch ----------------

extern "C" void kernel_launch(void* const* d_in, const int* in_sizes, int n_in,
                              void* d_out, int out_size, void* d_ws, size_t ws_size,
                              hipStream_t stream) {
    const float* x  = (const float*)d_in[0];
    const float* W1 = (const float*)d_in[1];
    const float* b1 = (const float*)d_in[2];
    const float* W3 = (const float*)d_in[3];
    const float* b3 = (const float*)d_in[4];
    const float* W4 = (const float*)d_in[5];
    const float* b4 = (const float*)d_in[6];
    const float* ew = (const float*)d_in[7];
    const int* ei   = (const int*)d_in[8];
    const int* src  = ei;
    const int* dst  = ei + EE;
    const int* batch = (const int*)d_in[9];

    float* out_embed = (float*)d_out;
    float* out_graph = out_embed + (size_t)NN * DD;

    char* w = (char*)d_ws;
    auto alloc = [&](size_t bytes) { char* p = w; w += (bytes + 255) & ~(size_t)255; return p; };
    u64* histo     = (u64*)  alloc((size_t)NCPY * NN * 8);   // 6.4 MB
    unsigned* rank = (unsigned*)alloc((size_t)EE * 4);
    float* dinv    = (float*)alloc((size_t)NN * 4);
    int*   cnts    = (int*)  alloc((size_t)NN * 4);
    unsigned char* xoffB = (unsigned char*)alloc((size_t)NN * NCPY);
    int2*  csr     = (int2*) alloc((size_t)NN * PAD * 8);    // 25.6 MB padded
    char*  xh      = alloc((size_t)NN * DD * 2);             // fp16 x
    char*  hh      = alloc((size_t)NN * DD * 2);             // fp16 h
    char*  ph      = alloc((size_t)NN * DD * 2);             // fp16 P2
    _Float16* w1t  = (_Float16*)alloc((size_t)DD * DD * 2);
    _Float16* w3t  = (_Float16*)alloc((size_t)DD * DD * 2);

    int nbN = (NN + 255) / 256;            // 196
    int nbE = (EE + 255) / 256;            // 3125
    int nbZ = (NCPY * NN + 255) / 256;     // 3125 (covers histo zero + x cvt)

    k_pre<<<nbZ, 256, 0, stream>>>(histo, out_graph, (const float4*)x, (uint4*)xh,
                                   W1, w1t, W3, w3t);
    k_hist<<<nbE, 256, 0, stream>>>(dst, ew, histo, rank);
    k_dinv<<<nbN, 256, 0, stream>>>(histo, dinv, cnts, xoffB);
    k_scatter<<<nbE, 256, 0, stream>>>(src, dst, ew, dinv, xoffB, rank, csr);

    // h = relu((A_hat x) W1 + b1) [fused gather+MFMA, fp16 out]
    k_prop_gemm<1><<<NN / 16, 192, 0, stream>>>((const uint4*)xh, csr, cnts, dinv,
                                                w1t, b1, (_Float16*)hh, nullptr, nullptr);
    // P2 = A_hat h [fp16, kept] ; embed = P2 W3 + b3 [fused, f32 out]
    k_prop_gemm<2><<<NN / 16, 192, 0, stream>>>((const uint4*)hh, csr, cnts, dinv,
                                                w3t, b3, nullptr, out_embed, (uint4*)ph);
    // out_graph = pool(P2) @ W4 + cnt * b4  (single-stage, distributed projection)
    k_pool<<<GG * 8, 256, 0, stream>>>((const __half*)ph, batch, W4, b4, out_graph);
}